// Round 19
// baseline (150.196 us; speedup 1.0000x reference)
//
#include <hip/hip_runtime.h>
#include <stdint.h>
#include <stddef.h>

typedef __attribute__((ext_vector_type(4))) float f32x4;
typedef __attribute__((ext_vector_type(16))) float f32x16;
typedef __attribute__((ext_vector_type(8))) short s16x8;
typedef __attribute__((ext_vector_type(4))) short s16x4;

#define MFMA_BF16(A, B, C) __builtin_amdgcn_mfma_f32_16x16x32_bf16(A, B, C, 0, 0, 0)
#define MFMA32_BF16(A, B, C) __builtin_amdgcn_mfma_f32_32x32x16_bf16(A, B, C, 0, 0, 0)

__device__ __forceinline__ short f2bf(float x) {
  union { float f; unsigned u; } v; v.f = x;
  unsigned r = v.u + 0x7fffu + ((v.u >> 16) & 1u);   // RTNE
  return (short)(r >> 16);
}

__device__ __forceinline__ unsigned cvt_pk_bf16(float lo, float hi) {
  unsigned r;
  asm("v_cvt_pk_bf16_f32 %0, %1, %2" : "=v"(r) : "v"(lo), "v"(hi));
  return r;
}

__device__ __forceinline__ void pl32swap(unsigned& x, unsigned& y) {
  asm volatile("v_permlane32_swap_b32 %0, %1" : "+v"(x), "+v"(y));
}

__device__ __forceinline__ void gload_lds16(const void* g, void* l) {
  __builtin_amdgcn_global_load_lds(
      (const __attribute__((address_space(1))) unsigned int*)g,
      (__attribute__((address_space(3))) unsigned int*)l, 16, 0, 0);
}

// ---------------------------------------------------------------- cast f32->bf16
// W_q pre-scaled by 1/sqrt(64)*log2(e): scores come out of QK^T in exp2 units.
__global__ __launch_bounds__(256) void cast_all(
    const float* __restrict__ x, const float* __restrict__ wq,
    const float* __restrict__ wk, const float* __restrict__ wv,
    const float* __restrict__ wo, short* __restrict__ xb,
    short* __restrict__ wqb, short* __restrict__ wkb, short* __restrict__ wvb,
    short* __restrict__ wob) {
  size_t i = ((size_t)blockIdx.x * 256 + threadIdx.x) * 4;
  const float* s; short* d; size_t off; float sc = 1.0f;
  if (i < (size_t)(8u << 20))       { s = x;  d = xb;  off = i; }
  else if (i < (size_t)(9u << 20))  { s = wq; d = wqb; off = i - (size_t)(8u << 20);
                                      sc = 0.18033688011112042f; }
  else if (i < (size_t)(10u << 20)) { s = wk; d = wkb; off = i - (size_t)(9u << 20); }
  else if (i < (size_t)(11u << 20)) { s = wv; d = wvb; off = i - (size_t)(10u << 20); }
  else                              { s = wo; d = wob; off = i - (size_t)(11u << 20); }
  float4 v = *(const float4*)(s + off);
  s16x4 o;
  o.x = f2bf(v.x * sc); o.y = f2bf(v.y * sc); o.z = f2bf(v.z * sc); o.w = f2bf(v.w * sc);
  *(s16x4*)(d + off) = o;
}

// ---------------------------------------------------------------- B^T GEMM
// C[m][n] = sum_k A[m*K+k]*B[n*K+k].  128x128 tile, BK=64, 4 waves (2x2 of 64x64).
// PIPELINED staging (ported from the r13 attn pipeline): double-buffered LDS,
// per K-step: barrier1 (all compute(k-1) done) -> issue STAGE(k+1) ->
// counted s_waitcnt vmcnt(8) (retire stage(k), keep stage(k+1) in flight) ->
// barrier2 (everyone's stage(k) landed) -> compute(k). No vmcnt(0) drain in
// the main loop; stage(k+1) latency hides under compute(k)'s 32 MFMAs.
// Safety: stage(k+1) writes buf[(k-1)&1], issued only after barrier1 which
// retires all its readers (compute(k-1)); barrier2 after per-wave vmcnt(8)
// ensures every wave's stage(k) landed before any wave reads buf[k&1].
// MODE 0: fused Q+K. B rows [0,1024)=Wq, [1024,2048)=Wk. bf16 scatter
//         [b,h,n,64] at C (+8M elems for K). Coalesced along d.
// MODE 1: V^T (m=dout, n=token) -> bf16 scatter [b,h,64,n]. Coalesced along n.
// MODE 2: f32 [m][n] + bias[n].
template <int MODE>
__global__ __launch_bounds__(256, 4) void gemm_bt(
    const short* __restrict__ A, const short* __restrict__ B,
    void* __restrict__ C, const float* __restrict__ bias, int M, int N, int K) {
  (void)M; (void)N;
  __shared__ short Asm[2][128 * 64];
  __shared__ short Bsm[2][128 * 64];
  const int tid = threadIdx.x;
  const int wave = tid >> 6, lane = tid & 63;
  const int l4 = lane >> 4, l15 = lane & 15;
  const int m0 = blockIdx.x * 128, n0 = blockIdx.y * 128;
  const int wr = wave >> 1, wc = wave & 1;

  f32x4 acc[4][4] = {};

  const int strow = wave * 8 + (lane >> 3);          // staging row (per 32-row round)
  const int sc = ((lane & 7) ^ (lane >> 3)) * 8;     // pre-swizzled source chunk
  const int chx = l15 & 7;                           // fragment-read xor

#define GSTAGE(bufi, k0_)                                                        \
  do {                                                                           \
    _Pragma("unroll") for (int i_ = 0; i_ < 4; ++i_) {                           \
      const int row_ = i_ * 32 + strow;                                          \
      gload_lds16(A + (size_t)(m0 + row_) * K + (k0_) + sc,                      \
                  &Asm[bufi][(i_ * 32 + wave * 8) * 64]);                        \
      gload_lds16(B + (size_t)(n0 + row_) * K + (k0_) + sc,                      \
                  &Bsm[bufi][(i_ * 32 + wave * 8) * 64]);                        \
    }                                                                            \
  } while (0)

  const int nk = K >> 6;               // 16 for K=1024
  GSTAGE(0, 0);
  for (int k = 0; k < nk; ++k) {
    __builtin_amdgcn_s_barrier();      // all waves finished compute(k-1)
    __builtin_amdgcn_sched_barrier(0);
    if (k + 1 < nk) {
      GSTAGE((k + 1) & 1, (k + 1) * 64);
      asm volatile("s_waitcnt vmcnt(8)" ::: "memory");   // stage(k) retired
    } else {
      asm volatile("s_waitcnt vmcnt(0)" ::: "memory");
    }
    __builtin_amdgcn_s_barrier();      // everyone's stage(k) landed
    __builtin_amdgcn_sched_barrier(0);

    const short* Ab = Asm[k & 1];
    const short* Bb = Bsm[k & 1];
#pragma unroll
    for (int kk = 0; kk < 2; ++kk) {
      const int ch = ((kk * 4 + l4) ^ chx) * 8;
      s16x8 af[4], bfr[4];
#pragma unroll
      for (int mi = 0; mi < 4; ++mi)
        af[mi] = *(const s16x8*)&Ab[(wr * 64 + mi * 16 + l15) * 64 + ch];
#pragma unroll
      for (int ni = 0; ni < 4; ++ni)
        bfr[ni] = *(const s16x8*)&Bb[(wc * 64 + ni * 16 + l15) * 64 + ch];
      __builtin_amdgcn_s_setprio(1);
#pragma unroll
      for (int mi = 0; mi < 4; ++mi)
#pragma unroll
        for (int ni = 0; ni < 4; ++ni)
          acc[mi][ni] = MFMA_BF16(af[mi], bfr[ni], acc[mi][ni]);
      __builtin_amdgcn_s_setprio(0);
    }
  }
#undef GSTAGE

  float bv[4];
  if constexpr (MODE == 2) {
#pragma unroll
    for (int ni = 0; ni < 4; ++ni) bv[ni] = bias[n0 + wc * 64 + ni * 16 + l15];
  }

#pragma unroll
  for (int mi = 0; mi < 4; ++mi) {
    const int rbase = m0 + wr * 64 + mi * 16 + l4 * 4;
#pragma unroll
    for (int ni = 0; ni < 4; ++ni) {
      const int nn = n0 + wc * 64 + ni * 16 + l15;
#pragma unroll
      for (int r = 0; r < 4; ++r) {
        const int mm = rbase + r;
        const float v = acc[mi][ni][r];
        if constexpr (MODE == 0) {
          const size_t pb = (size_t)(n0 >> 10) << 23;      // block-uniform Q/K select
          const int nn1 = nn & 1023;
          const int b = mm >> 11, n = mm & 2047, h = nn1 >> 6, d = nn1 & 63;
          ((short*)C)[pb + ((((size_t)(b * 16 + h) * 2048 + n) << 6) + d)] = f2bf(v);
        } else if constexpr (MODE == 1) {
          const int b = nn >> 11, n = nn & 2047, h = mm >> 6, d = mm & 63;
          ((short*)C)[((size_t)(b * 16 + h) * 64 + d) * 2048 + n] = f2bf(v);
        } else {
          ((float*)C)[(size_t)mm * 1024 + nn] = v + bv[ni];
        }
      }
    }
  }
}

// ---------------------------------------------------------------- flash attention
// Q,K: bf16 [b,h,2048,64]; Vt: bf16 [b,h,64,2048]; ctx: bf16 [b,2048,1024].
// 8 waves x 32 q-rows = 256 q/block sharing one K/V staging (each wave stages
// 8 K-rows + 8 V-rows per tile). 32x32x16 swapped QK^T; in-register softmax
// via cvt_pk + permlane32_swap; ones-MFMA denominator.
// PIPELINED staging (T3+T4): 4 LDS buffers, 2 tiles prefetched ahead, ONE raw
// s_barrier per tile with COUNTED s_waitcnt vmcnt(N) (never 0 in steady state)
// so prefetch loads stay in flight across the barrier.
// Safety: STAGE(t+2) overwrites buf[(t+2)&3], whose last readers (compute t-2)
// precede barrier(t-1) in all waves' program order; buffers t-1,t,t+1 distinct.
// Grid 512 heavy-first, 2 blocks/CU (LDS 64 KB).   [round-13 measured best]
__global__ __launch_bounds__(512, 4) void attn_fwd(
    const short* __restrict__ Qg, const short* __restrict__ Kg,
    const short* __restrict__ Vtg, short* __restrict__ ctx) {
  __shared__ short Ksm[4][64 * 64];    // [kv][d], chunk XOR by (kv&7)
  __shared__ short Vsm[4][64 * 64];    // [d][kv], chunk XOR by (d&7)

  const int tid = threadIdx.x;
  const int wave = tid >> 6, lane = tid & 63;   // wave in [0,8)
  const int c31 = lane & 31, h5 = lane >> 5;
  const int bx = blockIdx.x;
  const int bh = bx & 63;
  const int qi = 7 - (bx >> 6);          // heavy q-tiles first
  const int b = bh >> 4, h = bh & 15;

  const size_t bq = (size_t)bh * 2048;   // token base (Q/K rows)
  const size_t bv = (size_t)bh * 64;     // d base (Vt rows)

  const int strow = wave * 8 + (lane >> 3);        // staging row in [0,64)
  const int sc = ((lane & 7) ^ (lane >> 3)) * 8;   // pre-swizzled source chunk
  const int chx = c31 & 7;                          // fragment-read xor

  s16x8 onesf;
#pragma unroll
  for (int i = 0; i < 8; ++i) onesf[i] = (short)0x3F80;  // bf16 1.0

#define STAGE(bufi, kv0_)                                                        \
  do {                                                                           \
    gload_lds16(Kg + (bq + (kv0_) + strow) * 64 + sc,                            \
                &Ksm[bufi][wave * 8 * 64]);                                      \
    gload_lds16(Vtg + (bv + strow) * 2048 + (kv0_) + sc,                         \
                &Vsm[bufi][wave * 8 * 64]);                                      \
  } while (0)

  const int q0w = qi * 256 + wave * 32;
  const int qg = q0w + c31;            // this lane's q (as S^T column)

  // Q B-fragments: lane holds Q[q0w+c31][s*16 + h5*8 .. +7]
  s16x8 qf[4];
  {
    const short* qrow = Qg + (bq + q0w + c31) * 64 + h5 * 8;
#pragma unroll
    for (int s = 0; s < 4; ++s) qf[s] = *(const s16x8*)(qrow + s * 16);
  }

  f32x16 acc[2] = {};    // [dh]: ctx cols dh*32+c31, q rows per reg
  f32x16 accl = {};      // softmax denominator, same q-reg mapping

  const int nt = 4 * qi + 4;           // nt >= 4 always
  STAGE(0, 0);
  STAGE(1, 64);
  for (int t = 0; t < nt; ++t) {
    if (t + 2 < nt) STAGE((t + 2) & 3, (t + 2) * 64);
    // counted wait: tiles t+1 (and t+2 if staged) remain in flight, 2 loads each
    const int inflight = (nt - 1 - t < 2) ? (nt - 1 - t) : 2;
    if (inflight == 2)      asm volatile("s_waitcnt vmcnt(4)" ::: "memory");
    else if (inflight == 1) asm volatile("s_waitcnt vmcnt(2)" ::: "memory");
    else                    asm volatile("s_waitcnt vmcnt(0)" ::: "memory");
    __builtin_amdgcn_s_barrier();
    __builtin_amdgcn_sched_barrier(0);

    const int kv0 = t * 64;
    if (kv0 > q0w + 31) continue;          // fully masked for this wave
    const short* Kb = Ksm[t & 3];
    const short* Vb = Vsm[t & 3];

    // S^T = K Q^T : st[kvh] reg r -> kv = kv0+kvh*32+(r&3)+8*(r>>2)+4*h5, q = qg
    f32x16 st[2] = {};
    __builtin_amdgcn_s_setprio(1);
#pragma unroll
    for (int s = 0; s < 4; ++s) {
      const int ch = ((2 * s + h5) ^ chx) * 8;
#pragma unroll
      for (int kvh = 0; kvh < 2; ++kvh) {
        const s16x8 kf = *(const s16x8*)&Kb[(kvh * 32 + c31) * 64 + ch];
        st[kvh] = MFMA32_BF16(kf, qf[s], st[kvh]);
      }
    }
    __builtin_amdgcn_s_setprio(0);

    // causal mask (wave-uniform outer test), then exp2
#pragma unroll
    for (int kvh = 0; kvh < 2; ++kvh) {
      if (kv0 + kvh * 32 + 31 > q0w) {
        const int kvb = kv0 + kvh * 32 + 4 * h5;
#pragma unroll
        for (int r = 0; r < 16; ++r) {
          const int kv = kvb + (r & 3) + 8 * (r >> 2);
          if (kv > qg) st[kvh][r] = -3e38f;
        }
      }
    }
    float pe[2][16];
#pragma unroll
    for (int kvh = 0; kvh < 2; ++kvh)
#pragma unroll
      for (int r = 0; r < 16; ++r)
        pe[kvh][r] = __builtin_amdgcn_exp2f(st[kvh][r]);

    // P A-fragments per 16-kv window: 4 cvt_pk + 2 permlane32_swap each
    s16x8 pa[4];
#pragma unroll
    for (int w = 0; w < 4; ++w) {
      const int kvh = w >> 1, m0 = (w & 1) * 8;
      unsigned X  = cvt_pk_bf16(pe[kvh][m0 + 0], pe[kvh][m0 + 1]);
      unsigned X2 = cvt_pk_bf16(pe[kvh][m0 + 2], pe[kvh][m0 + 3]);
      unsigned Y  = cvt_pk_bf16(pe[kvh][m0 + 4], pe[kvh][m0 + 5]);
      unsigned Y2 = cvt_pk_bf16(pe[kvh][m0 + 6], pe[kvh][m0 + 7]);
      pl32swap(X, Y);
      pl32swap(X2, Y2);
      union { s16x8 v; unsigned u[4]; } pu;
      pu.u[0] = X; pu.u[1] = X2; pu.u[2] = Y; pu.u[3] = Y2;
      pa[w] = pu.v;
    }

    // ctx += P V ; denom += P 1
    __builtin_amdgcn_s_setprio(1);
#pragma unroll
    for (int w = 0; w < 4; ++w) {
      accl = MFMA32_BF16(pa[w], onesf, accl);
      const int ch = ((2 * w + h5) ^ chx) * 8;
#pragma unroll
      for (int dh = 0; dh < 2; ++dh) {
        const s16x8 vf = *(const s16x8*)&Vb[(dh * 32 + c31) * 64 + ch];
        acc[dh] = MFMA32_BF16(pa[w], vf, acc[dh]);
      }
    }
    __builtin_amdgcn_s_setprio(0);
  }

  // epilogue: q per reg = q0w + (r&3)+8*(r>>2)+4*h5; d = h*64 + dh*32 + c31
#pragma unroll
  for (int r = 0; r < 16; ++r) {
    const float inv = 1.f / accl[r];
    const int q = q0w + (r & 3) + 8 * (r >> 2) + 4 * h5;
#pragma unroll
    for (int dh = 0; dh < 2; ++dh)
      ctx[((size_t)b * 2048 + q) * 1024 + h * 64 + dh * 32 + c31] =
          f2bf(acc[dh][r] * inv);
  }
#undef STAGE
}

// ---------------------------------------------------------------- launch
extern "C" void kernel_launch(void* const* d_in, const int* in_sizes, int n_in,
                              void* d_out, int out_size, void* d_ws, size_t ws_size,
                              hipStream_t stream) {
  (void)in_sizes; (void)n_in; (void)out_size; (void)ws_size;
  const float* x  = (const float*)d_in[0];
  const float* Wq = (const float*)d_in[1];
  const float* Wk = (const float*)d_in[2];
  const float* Wv = (const float*)d_in[3];
  const float* Wo = (const float*)d_in[4];
  const float* bo = (const float*)d_in[5];

  char* ws = (char*)d_ws;
  short* xb   = (short*)(ws);                      // 16 MB  x bf16
  short* wqb  = (short*)(ws + ((size_t)16 << 20)); //  2 MB  (wq|wk contiguous)
  short* wkb  = (short*)(ws + ((size_t)18 << 20));
  short* wvb  = (short*)(ws + ((size_t)20 << 20));
  short* wob  = (short*)(ws + ((size_t)22 << 20));
  short* qbuf = (short*)(ws + ((size_t)24 << 20)); // 16 MB  [b,h,n,64]; K at +8M, V^T at +16M
  short* ctxb = (short*)(ws + ((size_t)72 << 20)); // 16 MB  [b,n,1024]

  cast_all<<<12288, 256, 0, stream>>>(x, Wq, Wk, Wv, Wo, xb, wqb, wkb, wvb, wob);
  // fused Q+K (B = [Wq;Wk] contiguous, N=2048, coalesced scatter)
  gemm_bt<0><<<dim3(64, 16), 256, 0, stream>>>(xb, wqb, qbuf, nullptr, 8192, 2048, 1024);
  // V^T with m=dout (coalesced along tokens)
  gemm_bt<1><<<dim3(8, 64), 256, 0, stream>>>(wvb, xb, qbuf + ((size_t)16 << 20),
                                              nullptr, 1024, 8192, 1024);
  attn_fwd<<<dim3(512), 512, 0, stream>>>(qbuf, qbuf + ((size_t)8 << 20),
                                          qbuf + ((size_t)16 << 20), ctxb);
  gemm_bt<2><<<dim3(64, 8), 256, 0, stream>>>(ctxb, wob, d_out, bo, 8192, 1024, 1024);
}

// Round 20
// 143.235 us; speedup vs baseline: 1.0486x; 1.0486x over previous
//
#include <hip/hip_runtime.h>
#include <stdint.h>
#include <stddef.h>

typedef __attribute__((ext_vector_type(4))) float f32x4;
typedef __attribute__((ext_vector_type(16))) float f32x16;
typedef __attribute__((ext_vector_type(8))) short s16x8;
typedef __attribute__((ext_vector_type(4))) short s16x4;

#define MFMA_BF16(A, B, C) __builtin_amdgcn_mfma_f32_16x16x32_bf16(A, B, C, 0, 0, 0)
#define MFMA32_BF16(A, B, C) __builtin_amdgcn_mfma_f32_32x32x16_bf16(A, B, C, 0, 0, 0)

__device__ __forceinline__ short f2bf(float x) {
  union { float f; unsigned u; } v; v.f = x;
  unsigned r = v.u + 0x7fffu + ((v.u >> 16) & 1u);   // RTNE
  return (short)(r >> 16);
}

__device__ __forceinline__ unsigned cvt_pk_bf16(float lo, float hi) {
  unsigned r;
  asm("v_cvt_pk_bf16_f32 %0, %1, %2" : "=v"(r) : "v"(lo), "v"(hi));
  return r;
}

__device__ __forceinline__ void pl32swap(unsigned& x, unsigned& y) {
  asm volatile("v_permlane32_swap_b32 %0, %1" : "+v"(x), "+v"(y));
}

__device__ __forceinline__ void gload_lds16(const void* g, void* l) {
  __builtin_amdgcn_global_load_lds(
      (const __attribute__((address_space(1))) unsigned int*)g,
      (__attribute__((address_space(3))) unsigned int*)l, 16, 0, 0);
}

// ---------------------------------------------------------------- cast f32->bf16
// W_q pre-scaled by 1/sqrt(64)*log2(e): scores come out of QK^T in exp2 units.
__global__ __launch_bounds__(256) void cast_all(
    const float* __restrict__ x, const float* __restrict__ wq,
    const float* __restrict__ wk, const float* __restrict__ wv,
    const float* __restrict__ wo, short* __restrict__ xb,
    short* __restrict__ wqb, short* __restrict__ wkb, short* __restrict__ wvb,
    short* __restrict__ wob) {
  size_t i = ((size_t)blockIdx.x * 256 + threadIdx.x) * 4;
  const float* s; short* d; size_t off; float sc = 1.0f;
  if (i < (size_t)(8u << 20))       { s = x;  d = xb;  off = i; }
  else if (i < (size_t)(9u << 20))  { s = wq; d = wqb; off = i - (size_t)(8u << 20);
                                      sc = 0.18033688011112042f; }
  else if (i < (size_t)(10u << 20)) { s = wk; d = wkb; off = i - (size_t)(9u << 20); }
  else if (i < (size_t)(11u << 20)) { s = wv; d = wvb; off = i - (size_t)(10u << 20); }
  else                              { s = wo; d = wob; off = i - (size_t)(11u << 20); }
  float4 v = *(const float4*)(s + off);
  s16x4 o;
  o.x = f2bf(v.x * sc); o.y = f2bf(v.y * sc); o.z = f2bf(v.z * sc); o.w = f2bf(v.w * sc);
  *(s16x4*)(d + off) = o;
}

// ---------------------------------------------------------------- B^T GEMM
// C[m][n] = sum_k A[m*K+k]*B[n*K+k].  128x128 tile, BK=64, 4 waves (2x2 of 64x64).
// Single-buffer (32 KB LDS -> 4 blocks/CU; r19 lesson: double-buffer halves
// residency and loses more than counted-vmcnt gains — inter-block overlap
// already hides the barrier drain at 4 blocks/CU).
// MODE 0: fused Q+K. B rows [0,1024)=Wq, [1024,2048)=Wk. bf16 scatter
//         [b,h,n,64] at C (+8M elems for K). Coalesced along d.
// MODE 1: V^T (m=dout, n=token) -> bf16 scatter [b,h,64,n]. Coalesced along n.
// MODE 2: f32 [m][n] + bias[n].
template <int MODE>
__global__ __launch_bounds__(256, 4) void gemm_bt(
    const short* __restrict__ A, const short* __restrict__ B,
    void* __restrict__ C, const float* __restrict__ bias, int M, int N, int K) {
  (void)M; (void)N;
  __shared__ short Asm[128 * 64];
  __shared__ short Bsm[128 * 64];
  const int tid = threadIdx.x;
  const int wave = tid >> 6, lane = tid & 63;
  const int l4 = lane >> 4, l15 = lane & 15;
  const int m0 = blockIdx.x * 128, n0 = blockIdx.y * 128;
  const int wr = wave >> 1, wc = wave & 1;

  f32x4 acc[4][4] = {};

  const int strow = wave * 8 + (lane >> 3);          // staging row (per 32-row round)
  const int sc = ((lane & 7) ^ (lane >> 3)) * 8;     // pre-swizzled source chunk
  const int chx = l15 & 7;                           // fragment-read xor

  for (int k0 = 0; k0 < K; k0 += 64) {
    __syncthreads();
#pragma unroll
    for (int i = 0; i < 4; ++i) {
      const int row = i * 32 + strow;
      gload_lds16(A + (size_t)(m0 + row) * K + k0 + sc, &Asm[(i * 32 + wave * 8) * 64]);
      gload_lds16(B + (size_t)(n0 + row) * K + k0 + sc, &Bsm[(i * 32 + wave * 8) * 64]);
    }
    __syncthreads();
#pragma unroll
    for (int kk = 0; kk < 2; ++kk) {
      const int ch = ((kk * 4 + l4) ^ chx) * 8;
      s16x8 af[4], bfr[4];
#pragma unroll
      for (int mi = 0; mi < 4; ++mi)
        af[mi] = *(const s16x8*)&Asm[(wr * 64 + mi * 16 + l15) * 64 + ch];
#pragma unroll
      for (int ni = 0; ni < 4; ++ni)
        bfr[ni] = *(const s16x8*)&Bsm[(wc * 64 + ni * 16 + l15) * 64 + ch];
      __builtin_amdgcn_s_setprio(1);
#pragma unroll
      for (int mi = 0; mi < 4; ++mi)
#pragma unroll
        for (int ni = 0; ni < 4; ++ni)
          acc[mi][ni] = MFMA_BF16(af[mi], bfr[ni], acc[mi][ni]);
      __builtin_amdgcn_s_setprio(0);
    }
  }

  float bv[4];
  if constexpr (MODE == 2) {
#pragma unroll
    for (int ni = 0; ni < 4; ++ni) bv[ni] = bias[n0 + wc * 64 + ni * 16 + l15];
  }

#pragma unroll
  for (int mi = 0; mi < 4; ++mi) {
    const int rbase = m0 + wr * 64 + mi * 16 + l4 * 4;
#pragma unroll
    for (int ni = 0; ni < 4; ++ni) {
      const int nn = n0 + wc * 64 + ni * 16 + l15;
#pragma unroll
      for (int r = 0; r < 4; ++r) {
        const int mm = rbase + r;
        const float v = acc[mi][ni][r];
        if constexpr (MODE == 0) {
          const size_t pb = (size_t)(n0 >> 10) << 23;      // block-uniform Q/K select
          const int nn1 = nn & 1023;
          const int b = mm >> 11, n = mm & 2047, h = nn1 >> 6, d = nn1 & 63;
          ((short*)C)[pb + ((((size_t)(b * 16 + h) * 2048 + n) << 6) + d)] = f2bf(v);
        } else if constexpr (MODE == 1) {
          const int b = nn >> 11, n = nn & 2047, h = mm >> 6, d = mm & 63;
          ((short*)C)[((size_t)(b * 16 + h) * 64 + d) * 2048 + n] = f2bf(v);
        } else {
          ((float*)C)[(size_t)mm * 1024 + nn] = v + bv[ni];
        }
      }
    }
  }
}

// ---------------------------------------------------------------- flash attention
// Q,K: bf16 [b,h,2048,64]; Vt: bf16 [b,h,64,2048]; ctx: bf16 [b,2048,1024].
// 8 waves x 32 q-rows = 256 q/block sharing one K/V staging (each wave stages
// 8 K-rows + 8 V-rows per tile). 32x32x16 swapped QK^T; in-register softmax
// via cvt_pk + permlane32_swap; ones-MFMA denominator.
// PIPELINED staging (T3+T4): 4 LDS buffers, 2 tiles prefetched ahead, ONE raw
// s_barrier per tile with COUNTED s_waitcnt vmcnt(N) (never 0 in steady state)
// so prefetch loads stay in flight across the barrier.
// Safety: STAGE(t+2) overwrites buf[(t+2)&3], whose last readers (compute t-2)
// precede barrier(t-1) in all waves' program order; buffers t-1,t,t+1 distinct.
// Grid 512 heavy-first, 2 blocks/CU (LDS 64 KB).   [round-13/18 measured best]
__global__ __launch_bounds__(512, 4) void attn_fwd(
    const short* __restrict__ Qg, const short* __restrict__ Kg,
    const short* __restrict__ Vtg, short* __restrict__ ctx) {
  __shared__ short Ksm[4][64 * 64];    // [kv][d], chunk XOR by (kv&7)
  __shared__ short Vsm[4][64 * 64];    // [d][kv], chunk XOR by (d&7)

  const int tid = threadIdx.x;
  const int wave = tid >> 6, lane = tid & 63;   // wave in [0,8)
  const int c31 = lane & 31, h5 = lane >> 5;
  const int bx = blockIdx.x;
  const int bh = bx & 63;
  const int qi = 7 - (bx >> 6);          // heavy q-tiles first
  const int b = bh >> 4, h = bh & 15;

  const size_t bq = (size_t)bh * 2048;   // token base (Q/K rows)
  const size_t bv = (size_t)bh * 64;     // d base (Vt rows)

  const int strow = wave * 8 + (lane >> 3);        // staging row in [0,64)
  const int sc = ((lane & 7) ^ (lane >> 3)) * 8;   // pre-swizzled source chunk
  const int chx = c31 & 7;                          // fragment-read xor

  s16x8 onesf;
#pragma unroll
  for (int i = 0; i < 8; ++i) onesf[i] = (short)0x3F80;  // bf16 1.0

#define STAGE(bufi, kv0_)                                                        \
  do {                                                                           \
    gload_lds16(Kg + (bq + (kv0_) + strow) * 64 + sc,                            \
                &Ksm[bufi][wave * 8 * 64]);                                      \
    gload_lds16(Vtg + (bv + strow) * 2048 + (kv0_) + sc,                         \
                &Vsm[bufi][wave * 8 * 64]);                                      \
  } while (0)

  const int q0w = qi * 256 + wave * 32;
  const int qg = q0w + c31;            // this lane's q (as S^T column)

  // Q B-fragments: lane holds Q[q0w+c31][s*16 + h5*8 .. +7]
  s16x8 qf[4];
  {
    const short* qrow = Qg + (bq + q0w + c31) * 64 + h5 * 8;
#pragma unroll
    for (int s = 0; s < 4; ++s) qf[s] = *(const s16x8*)(qrow + s * 16);
  }

  f32x16 acc[2] = {};    // [dh]: ctx cols dh*32+c31, q rows per reg
  f32x16 accl = {};      // softmax denominator, same q-reg mapping

  const int nt = 4 * qi + 4;           // nt >= 4 always
  STAGE(0, 0);
  STAGE(1, 64);
  for (int t = 0; t < nt; ++t) {
    if (t + 2 < nt) STAGE((t + 2) & 3, (t + 2) * 64);
    // counted wait: tiles t+1 (and t+2 if staged) remain in flight, 2 loads each
    const int inflight = (nt - 1 - t < 2) ? (nt - 1 - t) : 2;
    if (inflight == 2)      asm volatile("s_waitcnt vmcnt(4)" ::: "memory");
    else if (inflight == 1) asm volatile("s_waitcnt vmcnt(2)" ::: "memory");
    else                    asm volatile("s_waitcnt vmcnt(0)" ::: "memory");
    __builtin_amdgcn_s_barrier();
    __builtin_amdgcn_sched_barrier(0);

    const int kv0 = t * 64;
    if (kv0 > q0w + 31) continue;          // fully masked for this wave
    const short* Kb = Ksm[t & 3];
    const short* Vb = Vsm[t & 3];

    // S^T = K Q^T : st[kvh] reg r -> kv = kv0+kvh*32+(r&3)+8*(r>>2)+4*h5, q = qg
    f32x16 st[2] = {};
    __builtin_amdgcn_s_setprio(1);
#pragma unroll
    for (int s = 0; s < 4; ++s) {
      const int ch = ((2 * s + h5) ^ chx) * 8;
#pragma unroll
      for (int kvh = 0; kvh < 2; ++kvh) {
        const s16x8 kf = *(const s16x8*)&Kb[(kvh * 32 + c31) * 64 + ch];
        st[kvh] = MFMA32_BF16(kf, qf[s], st[kvh]);
      }
    }
    __builtin_amdgcn_s_setprio(0);

    // causal mask (wave-uniform outer test), then exp2
#pragma unroll
    for (int kvh = 0; kvh < 2; ++kvh) {
      if (kv0 + kvh * 32 + 31 > q0w) {
        const int kvb = kv0 + kvh * 32 + 4 * h5;
#pragma unroll
        for (int r = 0; r < 16; ++r) {
          const int kv = kvb + (r & 3) + 8 * (r >> 2);
          if (kv > qg) st[kvh][r] = -3e38f;
        }
      }
    }
    float pe[2][16];
#pragma unroll
    for (int kvh = 0; kvh < 2; ++kvh)
#pragma unroll
      for (int r = 0; r < 16; ++r)
        pe[kvh][r] = __builtin_amdgcn_exp2f(st[kvh][r]);

    // P A-fragments per 16-kv window: 4 cvt_pk + 2 permlane32_swap each
    s16x8 pa[4];
#pragma unroll
    for (int w = 0; w < 4; ++w) {
      const int kvh = w >> 1, m0 = (w & 1) * 8;
      unsigned X  = cvt_pk_bf16(pe[kvh][m0 + 0], pe[kvh][m0 + 1]);
      unsigned X2 = cvt_pk_bf16(pe[kvh][m0 + 2], pe[kvh][m0 + 3]);
      unsigned Y  = cvt_pk_bf16(pe[kvh][m0 + 4], pe[kvh][m0 + 5]);
      unsigned Y2 = cvt_pk_bf16(pe[kvh][m0 + 6], pe[kvh][m0 + 7]);
      pl32swap(X, Y);
      pl32swap(X2, Y2);
      union { s16x8 v; unsigned u[4]; } pu;
      pu.u[0] = X; pu.u[1] = X2; pu.u[2] = Y; pu.u[3] = Y2;
      pa[w] = pu.v;
    }

    // ctx += P V ; denom += P 1
    __builtin_amdgcn_s_setprio(1);
#pragma unroll
    for (int w = 0; w < 4; ++w) {
      accl = MFMA32_BF16(pa[w], onesf, accl);
      const int ch = ((2 * w + h5) ^ chx) * 8;
#pragma unroll
      for (int dh = 0; dh < 2; ++dh) {
        const s16x8 vf = *(const s16x8*)&Vb[(dh * 32 + c31) * 64 + ch];
        acc[dh] = MFMA32_BF16(pa[w], vf, acc[dh]);
      }
    }
    __builtin_amdgcn_s_setprio(0);
  }

  // epilogue: q per reg = q0w + (r&3)+8*(r>>2)+4*h5; d = h*64 + dh*32 + c31
#pragma unroll
  for (int r = 0; r < 16; ++r) {
    const float inv = 1.f / accl[r];
    const int q = q0w + (r & 3) + 8 * (r >> 2) + 4 * h5;
#pragma unroll
    for (int dh = 0; dh < 2; ++dh)
      ctx[((size_t)b * 2048 + q) * 1024 + h * 64 + dh * 32 + c31] =
          f2bf(acc[dh][r] * inv);
  }
#undef STAGE
}

// ---------------------------------------------------------------- launch
extern "C" void kernel_launch(void* const* d_in, const int* in_sizes, int n_in,
                              void* d_out, int out_size, void* d_ws, size_t ws_size,
                              hipStream_t stream) {
  (void)in_sizes; (void)n_in; (void)out_size; (void)ws_size;
  const float* x  = (const float*)d_in[0];
  const float* Wq = (const float*)d_in[1];
  const float* Wk = (const float*)d_in[2];
  const float* Wv = (const float*)d_in[3];
  const float* Wo = (const float*)d_in[4];
  const float* bo = (const float*)d_in[5];

  char* ws = (char*)d_ws;
  short* xb   = (short*)(ws);                      // 16 MB  x bf16
  short* wqb  = (short*)(ws + ((size_t)16 << 20)); //  2 MB  (wq|wk contiguous)
  short* wkb  = (short*)(ws + ((size_t)18 << 20));
  short* wvb  = (short*)(ws + ((size_t)20 << 20));
  short* wob  = (short*)(ws + ((size_t)22 << 20));
  short* qbuf = (short*)(ws + ((size_t)24 << 20)); // 16 MB  [b,h,n,64]; K at +8M, V^T at +16M
  short* ctxb = (short*)(ws + ((size_t)72 << 20)); // 16 MB  [b,n,1024]

  cast_all<<<12288, 256, 0, stream>>>(x, Wq, Wk, Wv, Wo, xb, wqb, wkb, wvb, wob);
  // fused Q+K (B = [Wq;Wk] contiguous, N=2048, coalesced scatter)
  gemm_bt<0><<<dim3(64, 16), 256, 0, stream>>>(xb, wqb, qbuf, nullptr, 8192, 2048, 1024);
  // V^T with m=dout (coalesced along tokens)
  gemm_bt<1><<<dim3(8, 64), 256, 0, stream>>>(wvb, xb, qbuf + ((size_t)16 << 20),
                                              nullptr, 1024, 8192, 1024);
  attn_fwd<<<dim3(512), 512, 0, stream>>>(qbuf, qbuf + ((size_t)8 << 20),
                                          qbuf + ((size_t)16 << 20), ctxb);
  gemm_bt<2><<<dim3(64, 8), 256, 0, stream>>>(ctxb, wob, d_out, bo, 8192, 1024, 1024);
}

// Round 21
// 140.153 us; speedup vs baseline: 1.0717x; 1.0220x over previous
//
#include <hip/hip_runtime.h>
#include <stdint.h>
#include <stddef.h>

typedef __attribute__((ext_vector_type(4))) float f32x4;
typedef __attribute__((ext_vector_type(16))) float f32x16;
typedef __attribute__((ext_vector_type(8))) short s16x8;
typedef __attribute__((ext_vector_type(4))) short s16x4;

#define MFMA_BF16(A, B, C) __builtin_amdgcn_mfma_f32_16x16x32_bf16(A, B, C, 0, 0, 0)
#define MFMA32_BF16(A, B, C) __builtin_amdgcn_mfma_f32_32x32x16_bf16(A, B, C, 0, 0, 0)

__device__ __forceinline__ short f2bf(float x) {
  union { float f; unsigned u; } v; v.f = x;
  unsigned r = v.u + 0x7fffu + ((v.u >> 16) & 1u);   // RTNE
  return (short)(r >> 16);
}

__device__ __forceinline__ unsigned cvt_pk_bf16(float lo, float hi) {
  unsigned r;
  asm("v_cvt_pk_bf16_f32 %0, %1, %2" : "=v"(r) : "v"(lo), "v"(hi));
  return r;
}

__device__ __forceinline__ void pl32swap(unsigned& x, unsigned& y) {
  asm volatile("v_permlane32_swap_b32 %0, %1" : "+v"(x), "+v"(y));
}

__device__ __forceinline__ void gload_lds16(const void* g, void* l) {
  __builtin_amdgcn_global_load_lds(
      (const __attribute__((address_space(1))) unsigned int*)g,
      (__attribute__((address_space(3))) unsigned int*)l, 16, 0, 0);
}

// ---------------------------------------------------------------- cast f32->bf16
// W_q pre-scaled by 1/sqrt(64)*log2(e): scores come out of QK^T in exp2 units.
__global__ __launch_bounds__(256) void cast_all(
    const float* __restrict__ x, const float* __restrict__ wq,
    const float* __restrict__ wk, const float* __restrict__ wv,
    const float* __restrict__ wo, short* __restrict__ xb,
    short* __restrict__ wqb, short* __restrict__ wkb, short* __restrict__ wvb,
    short* __restrict__ wob) {
  size_t i = ((size_t)blockIdx.x * 256 + threadIdx.x) * 4;
  const float* s; short* d; size_t off; float sc = 1.0f;
  if (i < (size_t)(8u << 20))       { s = x;  d = xb;  off = i; }
  else if (i < (size_t)(9u << 20))  { s = wq; d = wqb; off = i - (size_t)(8u << 20);
                                      sc = 0.18033688011112042f; }
  else if (i < (size_t)(10u << 20)) { s = wk; d = wkb; off = i - (size_t)(9u << 20); }
  else if (i < (size_t)(11u << 20)) { s = wv; d = wvb; off = i - (size_t)(10u << 20); }
  else                              { s = wo; d = wob; off = i - (size_t)(11u << 20); }
  float4 v = *(const float4*)(s + off);
  s16x4 o;
  o.x = f2bf(v.x * sc); o.y = f2bf(v.y * sc); o.z = f2bf(v.z * sc); o.w = f2bf(v.w * sc);
  *(s16x4*)(d + off) = o;
}

// ---------------------------------------------------------------- B^T GEMM
// C[m][n] = sum_k A[m*K+k]*B[n*K+k].  128x128 tile, BK=64, 4 waves (2x2 of 64x64).
// Single-buffer (32 KB LDS -> 4 blocks/CU; r19 lesson: double-buffer halves
// residency and loses more than counted-vmcnt gains — inter-block overlap
// already hides the barrier drain at 4 blocks/CU).
// MODE 0: fused Q+K. B rows [0,1024)=Wq, [1024,2048)=Wk. bf16 scatter
//         [b,h,n,64] at C (+8M elems for K). Coalesced along d.
// MODE 1: V^T (m=dout, n=token) -> bf16 scatter [b,h,64,n]. Coalesced along n.
// MODE 2: f32 [m][n] + bias[n].
template <int MODE>
__global__ __launch_bounds__(256, 4) void gemm_bt(
    const short* __restrict__ A, const short* __restrict__ B,
    void* __restrict__ C, const float* __restrict__ bias, int M, int N, int K) {
  (void)M; (void)N;
  __shared__ short Asm[128 * 64];
  __shared__ short Bsm[128 * 64];
  const int tid = threadIdx.x;
  const int wave = tid >> 6, lane = tid & 63;
  const int l4 = lane >> 4, l15 = lane & 15;
  const int m0 = blockIdx.x * 128, n0 = blockIdx.y * 128;
  const int wr = wave >> 1, wc = wave & 1;

  f32x4 acc[4][4] = {};

  const int strow = wave * 8 + (lane >> 3);          // staging row (per 32-row round)
  const int sc = ((lane & 7) ^ (lane >> 3)) * 8;     // pre-swizzled source chunk
  const int chx = l15 & 7;                           // fragment-read xor

  for (int k0 = 0; k0 < K; k0 += 64) {
    __syncthreads();
#pragma unroll
    for (int i = 0; i < 4; ++i) {
      const int row = i * 32 + strow;
      gload_lds16(A + (size_t)(m0 + row) * K + k0 + sc, &Asm[(i * 32 + wave * 8) * 64]);
      gload_lds16(B + (size_t)(n0 + row) * K + k0 + sc, &Bsm[(i * 32 + wave * 8) * 64]);
    }
    __syncthreads();
#pragma unroll
    for (int kk = 0; kk < 2; ++kk) {
      const int ch = ((kk * 4 + l4) ^ chx) * 8;
      s16x8 af[4], bfr[4];
#pragma unroll
      for (int mi = 0; mi < 4; ++mi)
        af[mi] = *(const s16x8*)&Asm[(wr * 64 + mi * 16 + l15) * 64 + ch];
#pragma unroll
      for (int ni = 0; ni < 4; ++ni)
        bfr[ni] = *(const s16x8*)&Bsm[(wc * 64 + ni * 16 + l15) * 64 + ch];
      __builtin_amdgcn_s_setprio(1);
#pragma unroll
      for (int mi = 0; mi < 4; ++mi)
#pragma unroll
        for (int ni = 0; ni < 4; ++ni)
          acc[mi][ni] = MFMA_BF16(af[mi], bfr[ni], acc[mi][ni]);
      __builtin_amdgcn_s_setprio(0);
    }
  }

  float bv[4];
  if constexpr (MODE == 2) {
#pragma unroll
    for (int ni = 0; ni < 4; ++ni) bv[ni] = bias[n0 + wc * 64 + ni * 16 + l15];
  }

#pragma unroll
  for (int mi = 0; mi < 4; ++mi) {
    const int rbase = m0 + wr * 64 + mi * 16 + l4 * 4;
#pragma unroll
    for (int ni = 0; ni < 4; ++ni) {
      const int nn = n0 + wc * 64 + ni * 16 + l15;
#pragma unroll
      for (int r = 0; r < 4; ++r) {
        const int mm = rbase + r;
        const float v = acc[mi][ni][r];
        if constexpr (MODE == 0) {
          const size_t pb = (size_t)(n0 >> 10) << 23;      // block-uniform Q/K select
          const int nn1 = nn & 1023;
          const int b = mm >> 11, n = mm & 2047, h = nn1 >> 6, d = nn1 & 63;
          ((short*)C)[pb + ((((size_t)(b * 16 + h) * 2048 + n) << 6) + d)] = f2bf(v);
        } else if constexpr (MODE == 1) {
          const int b = nn >> 11, n = nn & 2047, h = mm >> 6, d = mm & 63;
          ((short*)C)[((size_t)(b * 16 + h) * 64 + d) * 2048 + n] = f2bf(v);
        } else {
          ((float*)C)[(size_t)mm * 1024 + nn] = v + bv[ni];
        }
      }
    }
  }
}

// ---------------------------------------------------------------- flash attention
// Q,K: bf16 [b,h,2048,64]; Vt: bf16 [b,h,64,2048]; ctx: bf16 [b,2048,1024].
// 8 waves x 32 q-rows = 256 q/block sharing one K/V staging (each wave stages
// 8 K-rows + 8 V-rows per tile). 32x32x16 swapped QK^T; in-register softmax
// via cvt_pk + permlane32_swap; ones-MFMA denominator.
// PIPELINED staging (T3+T4): 4 LDS buffers, 2 tiles prefetched ahead, ONE raw
// s_barrier per tile with COUNTED s_waitcnt vmcnt(N) (never 0 in steady state).
// Safety: STAGE(t+2) overwrites buf[(t+2)&3], whose last readers (compute t-2)
// precede barrier(t-1) in all waves' program order; buffers t-1,t,t+1 distinct.
// Grid 512, 2 blocks/CU. COMPLEMENTARY qi mapping: under round-robin dispatch
// blocks bx and bx+256 co-reside on one CU; qi = (j<4 ? 7-j : j-4) pairs
// (7,0),(6,1),(5,2),(4,3) -> every CU carries exactly 36 tile-units (was
// 48/40/32/24 with plain heavy-first: 1.33x straggler).
__global__ __launch_bounds__(512, 4) void attn_fwd(
    const short* __restrict__ Qg, const short* __restrict__ Kg,
    const short* __restrict__ Vtg, short* __restrict__ ctx) {
  __shared__ short Ksm[4][64 * 64];    // [kv][d], chunk XOR by (kv&7)
  __shared__ short Vsm[4][64 * 64];    // [d][kv], chunk XOR by (d&7)

  const int tid = threadIdx.x;
  const int wave = tid >> 6, lane = tid & 63;   // wave in [0,8)
  const int c31 = lane & 31, h5 = lane >> 5;
  const int bx = blockIdx.x;
  const int bh = bx & 63;
  const int j = bx >> 6;                 // 0..7
  const int qi = (j < 4) ? (7 - j) : (j - 4);   // balanced co-resident pairs
  const int b = bh >> 4, h = bh & 15;

  const size_t bq = (size_t)bh * 2048;   // token base (Q/K rows)
  const size_t bv = (size_t)bh * 64;     // d base (Vt rows)

  const int strow = wave * 8 + (lane >> 3);        // staging row in [0,64)
  const int sc = ((lane & 7) ^ (lane >> 3)) * 8;   // pre-swizzled source chunk
  const int chx = c31 & 7;                          // fragment-read xor

  s16x8 onesf;
#pragma unroll
  for (int i = 0; i < 8; ++i) onesf[i] = (short)0x3F80;  // bf16 1.0

#define STAGE(bufi, kv0_)                                                        \
  do {                                                                           \
    gload_lds16(Kg + (bq + (kv0_) + strow) * 64 + sc,                            \
                &Ksm[bufi][wave * 8 * 64]);                                      \
    gload_lds16(Vtg + (bv + strow) * 2048 + (kv0_) + sc,                         \
                &Vsm[bufi][wave * 8 * 64]);                                      \
  } while (0)

  const int q0w = qi * 256 + wave * 32;
  const int qg = q0w + c31;            // this lane's q (as S^T column)

  // Q B-fragments: lane holds Q[q0w+c31][s*16 + h5*8 .. +7]
  s16x8 qf[4];
  {
    const short* qrow = Qg + (bq + q0w + c31) * 64 + h5 * 8;
#pragma unroll
    for (int s = 0; s < 4; ++s) qf[s] = *(const s16x8*)(qrow + s * 16);
  }

  f32x16 acc[2] = {};    // [dh]: ctx cols dh*32+c31, q rows per reg
  f32x16 accl = {};      // softmax denominator, same q-reg mapping

  const int nt = 4 * qi + 4;           // nt >= 4 always
  STAGE(0, 0);
  STAGE(1, 64);
  for (int t = 0; t < nt; ++t) {
    if (t + 2 < nt) STAGE((t + 2) & 3, (t + 2) * 64);
    // counted wait: tiles t+1 (and t+2 if staged) remain in flight, 2 loads each
    const int inflight = (nt - 1 - t < 2) ? (nt - 1 - t) : 2;
    if (inflight == 2)      asm volatile("s_waitcnt vmcnt(4)" ::: "memory");
    else if (inflight == 1) asm volatile("s_waitcnt vmcnt(2)" ::: "memory");
    else                    asm volatile("s_waitcnt vmcnt(0)" ::: "memory");
    __builtin_amdgcn_s_barrier();
    __builtin_amdgcn_sched_barrier(0);

    const int kv0 = t * 64;
    if (kv0 > q0w + 31) continue;          // fully masked for this wave
    const short* Kb = Ksm[t & 3];
    const short* Vb = Vsm[t & 3];

    // S^T = K Q^T : st[kvh] reg r -> kv = kv0+kvh*32+(r&3)+8*(r>>2)+4*h5, q = qg
    f32x16 st[2] = {};
    __builtin_amdgcn_s_setprio(1);
#pragma unroll
    for (int s = 0; s < 4; ++s) {
      const int ch = ((2 * s + h5) ^ chx) * 8;
#pragma unroll
      for (int kvh = 0; kvh < 2; ++kvh) {
        const s16x8 kf = *(const s16x8*)&Kb[(kvh * 32 + c31) * 64 + ch];
        st[kvh] = MFMA32_BF16(kf, qf[s], st[kvh]);
      }
    }
    __builtin_amdgcn_s_setprio(0);

    // causal mask (wave-uniform outer test), then exp2
#pragma unroll
    for (int kvh = 0; kvh < 2; ++kvh) {
      if (kv0 + kvh * 32 + 31 > q0w) {
        const int kvb = kv0 + kvh * 32 + 4 * h5;
#pragma unroll
        for (int r = 0; r < 16; ++r) {
          const int kv = kvb + (r & 3) + 8 * (r >> 2);
          if (kv > qg) st[kvh][r] = -3e38f;
        }
      }
    }
    float pe[2][16];
#pragma unroll
    for (int kvh = 0; kvh < 2; ++kvh)
#pragma unroll
      for (int r = 0; r < 16; ++r)
        pe[kvh][r] = __builtin_amdgcn_exp2f(st[kvh][r]);

    // P A-fragments per 16-kv window: 4 cvt_pk + 2 permlane32_swap each
    s16x8 pa[4];
#pragma unroll
    for (int w = 0; w < 4; ++w) {
      const int kvh = w >> 1, m0 = (w & 1) * 8;
      unsigned X  = cvt_pk_bf16(pe[kvh][m0 + 0], pe[kvh][m0 + 1]);
      unsigned X2 = cvt_pk_bf16(pe[kvh][m0 + 2], pe[kvh][m0 + 3]);
      unsigned Y  = cvt_pk_bf16(pe[kvh][m0 + 4], pe[kvh][m0 + 5]);
      unsigned Y2 = cvt_pk_bf16(pe[kvh][m0 + 6], pe[kvh][m0 + 7]);
      pl32swap(X, Y);
      pl32swap(X2, Y2);
      union { s16x8 v; unsigned u[4]; } pu;
      pu.u[0] = X; pu.u[1] = X2; pu.u[2] = Y; pu.u[3] = Y2;
      pa[w] = pu.v;
    }

    // ctx += P V ; denom += P 1
    __builtin_amdgcn_s_setprio(1);
#pragma unroll
    for (int w = 0; w < 4; ++w) {
      accl = MFMA32_BF16(pa[w], onesf, accl);
      const int ch = ((2 * w + h5) ^ chx) * 8;
#pragma unroll
      for (int dh = 0; dh < 2; ++dh) {
        const s16x8 vf = *(const s16x8*)&Vb[(dh * 32 + c31) * 64 + ch];
        acc[dh] = MFMA32_BF16(pa[w], vf, acc[dh]);
      }
    }
    __builtin_amdgcn_s_setprio(0);
  }

  // epilogue: q per reg = q0w + (r&3)+8*(r>>2)+4*h5; d = h*64 + dh*32 + c31
#pragma unroll
  for (int r = 0; r < 16; ++r) {
    const float inv = 1.f / accl[r];
    const int q = q0w + (r & 3) + 8 * (r >> 2) + 4 * h5;
#pragma unroll
    for (int dh = 0; dh < 2; ++dh)
      ctx[((size_t)b * 2048 + q) * 1024 + h * 64 + dh * 32 + c31] =
          f2bf(acc[dh][r] * inv);
  }
#undef STAGE
}

// ---------------------------------------------------------------- launch
extern "C" void kernel_launch(void* const* d_in, const int* in_sizes, int n_in,
                              void* d_out, int out_size, void* d_ws, size_t ws_size,
                              hipStream_t stream) {
  (void)in_sizes; (void)n_in; (void)out_size; (void)ws_size;
  const float* x  = (const float*)d_in[0];
  const float* Wq = (const float*)d_in[1];
  const float* Wk = (const float*)d_in[2];
  const float* Wv = (const float*)d_in[3];
  const float* Wo = (const float*)d_in[4];
  const float* bo = (const float*)d_in[5];

  char* ws = (char*)d_ws;
  short* xb   = (short*)(ws);                      // 16 MB  x bf16
  short* wqb  = (short*)(ws + ((size_t)16 << 20)); //  2 MB  (wq|wk contiguous)
  short* wkb  = (short*)(ws + ((size_t)18 << 20));
  short* wvb  = (short*)(ws + ((size_t)20 << 20));
  short* wob  = (short*)(ws + ((size_t)22 << 20));
  short* qbuf = (short*)(ws + ((size_t)24 << 20)); // 16 MB  [b,h,n,64]; K at +8M, V^T at +16M
  short* ctxb = (short*)(ws + ((size_t)72 << 20)); // 16 MB  [b,n,1024]

  cast_all<<<12288, 256, 0, stream>>>(x, Wq, Wk, Wv, Wo, xb, wqb, wkb, wvb, wob);
  // fused Q+K (B = [Wq;Wk] contiguous, N=2048, coalesced scatter)
  gemm_bt<0><<<dim3(64, 16), 256, 0, stream>>>(xb, wqb, qbuf, nullptr, 8192, 2048, 1024);
  // V^T with m=dout (coalesced along tokens)
  gemm_bt<1><<<dim3(8, 64), 256, 0, stream>>>(wvb, xb, qbuf + ((size_t)16 << 20),
                                              nullptr, 1024, 8192, 1024);
  attn_fwd<<<dim3(512), 512, 0, stream>>>(qbuf, qbuf + ((size_t)8 << 20),
                                          qbuf + ((size_t)16 << 20), ctxb);
  gemm_bt<2><<<dim3(64, 8), 256, 0, stream>>>(ctxb, wob, d_out, bo, 8192, 1024, 1024);
}